// Round 8
// baseline (2307.002 us; speedup 1.0000x reference)
//
#include <hip/hip_runtime.h>
#include <math.h>

// B=64, T=512, D=128, H=512, DS=32
#define BB 64
#define TT 512
#define DD 128
#define HH 512
#define DSZ 32
#define G4 2048
#define NBLK 64
#define NTHR 256
#define BBHH (BB * HH)
#define OUT_TAIL (BB * TT * DSZ)

typedef _Float16 f16;
typedef f16  f16x8 __attribute__((ext_vector_type(8)));
typedef f16  f16x4 __attribute__((ext_vector_type(4)));
typedef float f32x4 __attribute__((ext_vector_type(4)));

// ---- LLC-coherent (sc0 sc1) helpers: no fences, no L2 flushes ----
__device__ __forceinline__ void flag_store_sc(unsigned* p, unsigned v) {
    asm volatile("global_store_dword %0, %1, off sc0 sc1" :: "v"(p), "v"(v) : "memory");
}
__device__ __forceinline__ unsigned flag_load_sc(const unsigned* p) {
    unsigned v;
    asm volatile("global_load_dword %0, %1, off sc0 sc1\n\ts_waitcnt vmcnt(0)"
                 : "=v"(v) : "v"(p) : "memory");
    return v;
}

__device__ __forceinline__ float sigm(float x) {
    return __builtin_amdgcn_rcpf(1.f + __expf(-x));
}
__device__ __forceinline__ float tanh_fast(float x) {
    return 2.f * __builtin_amdgcn_rcpf(1.f + __expf(-2.f * x)) - 1.f;
}

// ---------------------------------------------------------------------------
// Pre-GEMM: xwT[t][gcol][b] (f16) = x[b,t,:] @ kern[:,gcol]  (bias NOT added)
// ---------------------------------------------------------------------------
__global__ __launch_bounds__(256) void xw_gemm(
    const float* __restrict__ x, const float* __restrict__ kern,
    f16* __restrict__ xwT)
{
    extern __shared__ f16 klds[];           // [512 cols][136]
    const int cc = blockIdx.x & 3;
    const int tg = blockIdx.x >> 2;
    const int tid = threadIdx.x;

    for (int idx = tid; idx < 512 * 128; idx += 256) {
        int k = idx >> 9, c = idx & 511;
        klds[c * 136 + k] = (f16)kern[(size_t)k * G4 + cc * 512 + c];
    }
    __syncthreads();

    const int wave = tid >> 6, lane = tid & 63;
    const int cidx = lane & 15;
    const int kseg = (lane >> 4) * 8;

    for (int t = tg * 4; t < tg * 4 + 4; ++t) {
        f16x8 Af[4][4];
        #pragma unroll
        for (int mt = 0; mt < 4; ++mt) {
            const float* xp = x + ((size_t)(mt * 16 + cidx) * TT + t) * DD + kseg;
            #pragma unroll
            for (int ks = 0; ks < 4; ++ks) {
                float4 a = *(const float4*)(xp + ks * 32);
                float4 b = *(const float4*)(xp + ks * 32 + 4);
                f16x8 f;
                f[0]=(f16)a.x; f[1]=(f16)a.y; f[2]=(f16)a.z; f[3]=(f16)a.w;
                f[4]=(f16)b.x; f[5]=(f16)b.y; f[6]=(f16)b.z; f[7]=(f16)b.w;
                Af[mt][ks] = f;
            }
        }
        for (int nt = 0; nt < 8; ++nt) {
            const int colc = (wave * 8 + nt) * 16 + cidx;
            f16x8 Bf[4];
            #pragma unroll
            for (int ks = 0; ks < 4; ++ks)
                Bf[ks] = *(const f16x8*)&klds[colc * 136 + ks * 32 + kseg];
            #pragma unroll
            for (int mt = 0; mt < 4; ++mt) {
                f32x4 a = {0.f, 0.f, 0.f, 0.f};
                #pragma unroll
                for (int ks = 0; ks < 4; ++ks)
                    a = __builtin_amdgcn_mfma_f32_16x16x32_f16(Af[mt][ks], Bf[ks], a, 0, 0, 0);
                f16x4 hv;
                #pragma unroll
                for (int r = 0; r < 4; ++r) hv[r] = (f16)a[r];
                const int gcol = cc * 512 + colc;
                const int brow = mt * 16 + (lane >> 4) * 4;
                *(f16x4*)(xwT + ((size_t)t * G4 + gcol) * BB + brow) = hv;
            }
        }
    }
}

// ---------------------------------------------------------------------------
// Persistent LSTM: 64 blocks x 256 thr (4 waves = 4 batch m-tiles).
// Sync path per step: ONE merged 64-flag poll (1 LLC trip), all 16 h-loads
// (1 trip, vmcnt(8)-split under MFMAs), LDS gate-pack + 1 barrier, then
// wave0 ALONE publishes 64 coalesced 16B sc-stores + flag while waves 1-3
// sprint ahead into the next step's poll. hpack double-buffered by t&1.
// ---------------------------------------------------------------------------
template<bool XW>
__global__ __launch_bounds__(NTHR, 1) void lstm_persist(
    const float* __restrict__ x, const float* __restrict__ kern,
    const float* __restrict__ rker, const float* __restrict__ bias,
    const f16* __restrict__ xwT, f16* __restrict__ seq16,
    f16* __restrict__ hbuf, unsigned* __restrict__ flags,
    float* __restrict__ out)
{
    __shared__ f16 hpack[2][64][8];   // [t&1][batch row][unit] = 2 KB

    const int tid = threadIdx.x, bid = blockIdx.x;
    const int wave = tid >> 6, lane = tid & 63;   // wave = batch m-tile
    const int c = lane & 15;
    const int q = lane >> 4;
    const int kseg = q * 8;
    const int arow = wave * 16 + c;               // A-frag batch row
    const int brow = wave * 16 + q * 4;           // C-frag batch row base
    const int u0 = c & 7;
    const int g0 = c >> 3;                        // 0 or 1
    const int j0 = bid * 8 + u0;
    const int gcolA = g0 * HH + j0;               // acc0 column (gate i/f)
    const int gcolB = (2 + g0) * HH + j0;         // acc1 column (gate g/o)

    // ---- one-time: recurrent weight fragments -> VGPRs (128 VGPRs) ----
    f16x8 wfA[16], wfB[16];
    #pragma unroll
    for (int ks = 0; ks < 16; ++ks) {
        f16x8 wa, wb;
        #pragma unroll
        for (int jj = 0; jj < 8; ++jj) {
            int k = ks * 32 + kseg + jj;
            wa[jj] = (f16)rker[(size_t)k * G4 + gcolA];
            wb[jj] = (f16)rker[(size_t)k * G4 + gcolB];
        }
        wfA[ks] = wa; wfB[ks] = wb;
    }
    f16x8 kfA[4], kfB[4];
    if (!XW) {
        #pragma unroll
        for (int ks = 0; ks < 4; ++ks) {
            f16x8 wa, wb;
            #pragma unroll
            for (int jj = 0; jj < 8; ++jj) {
                int k = ks * 32 + kseg + jj;
                wa[jj] = (f16)kern[(size_t)k * G4 + gcolA];
                wb[jj] = (f16)kern[(size_t)k * G4 + gcolB];
            }
            kfA[ks] = wa; kfB[ks] = wb;
        }
    }

    float bias4[4];
    #pragma unroll
    for (int g = 0; g < 4; ++g) bias4[g] = bias[g * HH + bid * 8 + u0];
    float creg[4] = {0.f, 0.f, 0.f, 0.f};

    for (int t = 0; t < TT; ++t) {
        // ---- acc init = x-projection (plain loads; drain overlaps poll) ----
        f32x4 acc0, acc1;
        if (XW) {
            f16x4 xa = *(const f16x4*)(xwT + ((size_t)t * G4 + gcolA) * BB + brow);
            f16x4 xb = *(const f16x4*)(xwT + ((size_t)t * G4 + gcolB) * BB + brow);
            #pragma unroll
            for (int r = 0; r < 4; ++r) { acc0[r] = (float)xa[r]; acc1[r] = (float)xb[r]; }
        } else {
            acc0 = (f32x4){0.f,0.f,0.f,0.f}; acc1 = (f32x4){0.f,0.f,0.f,0.f};
            const float* xp = x + ((size_t)arow * TT + t) * DD + kseg;
            #pragma unroll
            for (int ks = 0; ks < 4; ++ks) {
                float4 a = *(const float4*)(xp + ks * 32);
                float4 b = *(const float4*)(xp + ks * 32 + 4);
                f16x8 xa;
                xa[0]=(f16)a.x; xa[1]=(f16)a.y; xa[2]=(f16)a.z; xa[3]=(f16)a.w;
                xa[4]=(f16)b.x; xa[5]=(f16)b.y; xa[6]=(f16)b.z; xa[7]=(f16)b.w;
                acc0 = __builtin_amdgcn_mfma_f32_16x16x32_f16(xa, kfA[ks], acc0, 0, 0, 0);
                acc1 = __builtin_amdgcn_mfma_f32_16x16x32_f16(xa, kfB[ks], acc1, 0, 0, 0);
            }
        }

        if (t > 0) {
            // ---- ONE merged poll: lane L watches producer L (1 LLC trip) ----
            {
                const unsigned* fp = flags + (lane << 4);
                while ((int)flag_load_sc(fp) < t) {}
            }
            // ---- all 16 h-loads in one burst; vmcnt(8) releases first half ----
            const f16* hp = hbuf + ((t - 1) & 1) * BBHH + (size_t)arow * HH + kseg;
            f16x8 h0,h1,h2,h3,h4,h5,h6,h7,h8,h9,h10,h11,h12,h13,h14,h15;
            asm volatile(
                "global_load_dwordx4 %0, %16, off sc0 sc1\n\t"
                "global_load_dwordx4 %1, %16, off offset:64 sc0 sc1\n\t"
                "global_load_dwordx4 %2, %16, off offset:128 sc0 sc1\n\t"
                "global_load_dwordx4 %3, %16, off offset:192 sc0 sc1\n\t"
                "global_load_dwordx4 %4, %16, off offset:256 sc0 sc1\n\t"
                "global_load_dwordx4 %5, %16, off offset:320 sc0 sc1\n\t"
                "global_load_dwordx4 %6, %16, off offset:384 sc0 sc1\n\t"
                "global_load_dwordx4 %7, %16, off offset:448 sc0 sc1\n\t"
                "global_load_dwordx4 %8, %16, off offset:512 sc0 sc1\n\t"
                "global_load_dwordx4 %9, %16, off offset:576 sc0 sc1\n\t"
                "global_load_dwordx4 %10, %16, off offset:640 sc0 sc1\n\t"
                "global_load_dwordx4 %11, %16, off offset:704 sc0 sc1\n\t"
                "global_load_dwordx4 %12, %16, off offset:768 sc0 sc1\n\t"
                "global_load_dwordx4 %13, %16, off offset:832 sc0 sc1\n\t"
                "global_load_dwordx4 %14, %16, off offset:896 sc0 sc1\n\t"
                "global_load_dwordx4 %15, %16, off offset:960 sc0 sc1\n\t"
                "s_waitcnt vmcnt(8)"
                : "=&v"(h0),"=&v"(h1),"=&v"(h2),"=&v"(h3),
                  "=&v"(h4),"=&v"(h5),"=&v"(h6),"=&v"(h7),
                  "=&v"(h8),"=&v"(h9),"=&v"(h10),"=&v"(h11),
                  "=&v"(h12),"=&v"(h13),"=&v"(h14),"=&v"(h15)
                : "v"(hp) : "memory");
            __builtin_amdgcn_sched_barrier(0);
            // ---- MFMA ks 0..7 (second half still in flight) ----
            acc0 = __builtin_amdgcn_mfma_f32_16x16x32_f16(h0, wfA[0], acc0, 0, 0, 0);
            acc1 = __builtin_amdgcn_mfma_f32_16x16x32_f16(h0, wfB[0], acc1, 0, 0, 0);
            acc0 = __builtin_amdgcn_mfma_f32_16x16x32_f16(h1, wfA[1], acc0, 0, 0, 0);
            acc1 = __builtin_amdgcn_mfma_f32_16x16x32_f16(h1, wfB[1], acc1, 0, 0, 0);
            acc0 = __builtin_amdgcn_mfma_f32_16x16x32_f16(h2, wfA[2], acc0, 0, 0, 0);
            acc1 = __builtin_amdgcn_mfma_f32_16x16x32_f16(h2, wfB[2], acc1, 0, 0, 0);
            acc0 = __builtin_amdgcn_mfma_f32_16x16x32_f16(h3, wfA[3], acc0, 0, 0, 0);
            acc1 = __builtin_amdgcn_mfma_f32_16x16x32_f16(h3, wfB[3], acc1, 0, 0, 0);
            acc0 = __builtin_amdgcn_mfma_f32_16x16x32_f16(h4, wfA[4], acc0, 0, 0, 0);
            acc1 = __builtin_amdgcn_mfma_f32_16x16x32_f16(h4, wfB[4], acc1, 0, 0, 0);
            acc0 = __builtin_amdgcn_mfma_f32_16x16x32_f16(h5, wfA[5], acc0, 0, 0, 0);
            acc1 = __builtin_amdgcn_mfma_f32_16x16x32_f16(h5, wfB[5], acc1, 0, 0, 0);
            acc0 = __builtin_amdgcn_mfma_f32_16x16x32_f16(h6, wfA[6], acc0, 0, 0, 0);
            acc1 = __builtin_amdgcn_mfma_f32_16x16x32_f16(h6, wfB[6], acc1, 0, 0, 0);
            acc0 = __builtin_amdgcn_mfma_f32_16x16x32_f16(h7, wfA[7], acc0, 0, 0, 0);
            acc1 = __builtin_amdgcn_mfma_f32_16x16x32_f16(h7, wfB[7], acc1, 0, 0, 0);
            // ---- drain second half, MFMA ks 8..15 ----
            asm volatile("s_waitcnt vmcnt(0)"
                : "+v"(h8),"+v"(h9),"+v"(h10),"+v"(h11),
                  "+v"(h12),"+v"(h13),"+v"(h14),"+v"(h15));
            __builtin_amdgcn_sched_barrier(0);
            acc0 = __builtin_amdgcn_mfma_f32_16x16x32_f16(h8,  wfA[8],  acc0, 0, 0, 0);
            acc1 = __builtin_amdgcn_mfma_f32_16x16x32_f16(h8,  wfB[8],  acc1, 0, 0, 0);
            acc0 = __builtin_amdgcn_mfma_f32_16x16x32_f16(h9,  wfA[9],  acc0, 0, 0, 0);
            acc1 = __builtin_amdgcn_mfma_f32_16x16x32_f16(h9,  wfB[9],  acc1, 0, 0, 0);
            acc0 = __builtin_amdgcn_mfma_f32_16x16x32_f16(h10, wfA[10], acc0, 0, 0, 0);
            acc1 = __builtin_amdgcn_mfma_f32_16x16x32_f16(h10, wfB[10], acc1, 0, 0, 0);
            acc0 = __builtin_amdgcn_mfma_f32_16x16x32_f16(h11, wfA[11], acc0, 0, 0, 0);
            acc1 = __builtin_amdgcn_mfma_f32_16x16x32_f16(h11, wfB[11], acc1, 0, 0, 0);
            acc0 = __builtin_amdgcn_mfma_f32_16x16x32_f16(h12, wfA[12], acc0, 0, 0, 0);
            acc1 = __builtin_amdgcn_mfma_f32_16x16x32_f16(h12, wfB[12], acc1, 0, 0, 0);
            acc0 = __builtin_amdgcn_mfma_f32_16x16x32_f16(h13, wfA[13], acc0, 0, 0, 0);
            acc1 = __builtin_amdgcn_mfma_f32_16x16x32_f16(h13, wfB[13], acc1, 0, 0, 0);
            acc0 = __builtin_amdgcn_mfma_f32_16x16x32_f16(h14, wfA[14], acc0, 0, 0, 0);
            acc1 = __builtin_amdgcn_mfma_f32_16x16x32_f16(h14, wfB[14], acc1, 0, 0, 0);
            acc0 = __builtin_amdgcn_mfma_f32_16x16x32_f16(h15, wfA[15], acc0, 0, 0, 0);
            acc1 = __builtin_amdgcn_mfma_f32_16x16x32_f16(h15, wfB[15], acc1, 0, 0, 0);
        }

        // ---- gate exchange: lane c (<8) pairs with c^8 ----
        float zf_[4], zo_[4];
        #pragma unroll
        for (int r = 0; r < 4; ++r) {
            zf_[r] = __shfl_xor(acc0[r], 8);
            zo_[r] = __shfl_xor(acc1[r], 8);
        }
        if (c < 8) {   // leader: unit j0, rows brow..brow+3
            #pragma unroll
            for (int r = 0; r < 4; ++r) {
                float iv = sigm(acc0[r] + bias4[0]);
                float fv = sigm(zf_[r]  + bias4[1]);
                float gv = tanh_fast(acc1[r] + bias4[2]);
                float ov = sigm(zo_[r]  + bias4[3]);
                creg[r] = fv * creg[r] + iv * gv;
                float h = ov * tanh_fast(creg[r]);
                hpack[t & 1][brow + r][u0] = (f16)h;
                if (t == TT - 1) {
                    out[OUT_TAIL + (brow + r) * HH + j0] = h;
                    out[OUT_TAIL + BB * HH + (brow + r) * HH + j0] = creg[r];
                }
            }
        }
        __syncthreads();   // hpack visible block-wide; LDS-only drain (cheap)

        if (wave == 0) {
            // ---- publisher: 64 coalesced 16B sc stores + drain + flag ----
            f16x8 row = *(const f16x8*)&hpack[t & 1][lane][0];
            f16* dst = hbuf + (t & 1) * BBHH + (size_t)lane * HH + bid * 8;
            asm volatile(
                "global_store_dwordx4 %0, %1, off sc0 sc1\n\t"
                "s_waitcnt vmcnt(0)" :: "v"(dst), "v"(row) : "memory");
            if (lane == 0) flag_store_sc(flags + (bid << 4), (unsigned)(t + 1));
        } else if (wave == 1) {
            // ---- history mirror for dense stage (plain, off critical path) ----
            f16x8 row = *(const f16x8*)&hpack[t & 1][lane][0];
            *(f16x8*)(seq16 + (size_t)t * BBHH + (size_t)lane * HH + bid * 8) = row;
        }
        // waves 2,3 (and 1) run ahead into step t+1's xwT load + poll
    }
}

// ---------------------------------------------------------------------------
// Dense(32, tanh) via MFMA.
// ---------------------------------------------------------------------------
__global__ __launch_bounds__(256) void dense_mfma(
    const f16* __restrict__ seq16, const float* __restrict__ dw,
    const float* __restrict__ db, float* __restrict__ out)
{
    __shared__ f16 dwlds[32 * 520];
    const int tid = threadIdx.x;
    for (int idx = tid; idx < HH * DSZ; idx += 256) {
        int k = idx >> 5, n = idx & 31;
        dwlds[n * 520 + k] = (f16)dw[idx];
    }
    __syncthreads();

    const int wave = tid >> 6, lane = tid & 63;
    const int b0 = blockIdx.x & 63;
    const int t0 = (blockIdx.x >> 6) * 64 + wave * 16;
    const int kseg = (lane >> 4) * 8;
    const int col = lane & 15;

    const f16* ap = seq16 + ((size_t)(t0 + col) * BB + b0) * HH + kseg;

    f32x4 acc0 = {0.f, 0.f, 0.f, 0.f};
    f32x4 acc1 = {0.f, 0.f, 0.f, 0.f};
    #pragma unroll
    for (int ks = 0; ks < 16; ++ks) {
        f16x8 a  = *(const f16x8*)(ap + ks * 32);
        f16x8 w0 = *(const f16x8*)(dwlds + col * 520 + ks * 32 + kseg);
        f16x8 w1 = *(const f16x8*)(dwlds + (16 + col) * 520 + ks * 32 + kseg);
        acc0 = __builtin_amdgcn_mfma_f32_16x16x32_f16(a, w0, acc0, 0, 0, 0);
        acc1 = __builtin_amdgcn_mfma_f32_16x16x32_f16(a, w1, acc1, 0, 0, 0);
    }

    const float db0 = db[col], db1 = db[16 + col];
    #pragma unroll
    for (int r = 0; r < 4; ++r) {
        int t = t0 + (lane >> 4) * 4 + r;
        size_t base = (size_t)b0 * (TT * DSZ) + (size_t)t * DSZ;
        out[base + col]      = tanhf(acc0[r] + db0);
        out[base + 16 + col] = tanhf(acc1[r] + db1);
    }
}

extern "C" void kernel_launch(void* const* d_in, const int* in_sizes, int n_in,
                              void* d_out, int out_size, void* d_ws, size_t ws_size,
                              hipStream_t stream) {
    const float* x    = (const float*)d_in[0];
    const float* kern = (const float*)d_in[1];
    const float* rker = (const float*)d_in[2];
    const float* bias = (const float*)d_in[3];
    const float* dw   = (const float*)d_in[4];
    const float* db   = (const float*)d_in[5];
    float* out = (float*)d_out;

    char* ws = (char*)d_ws;
    f16* seq16 = (f16*)ws;                                   // 33,554,432 B
    f16* hbuf  = (f16*)(ws + 33554432);                      //    131,072 B
    unsigned* flags = (unsigned*)(ws + 33554432 + 131072);   //      4,096 B
    f16* xwT   = (f16*)(ws + 33689600);                      // 134,217,728 B

    const bool use_xw = (ws_size >= 33689600ull + 134217728ull);

    if (use_xw) {
        hipFuncSetAttribute(reinterpret_cast<const void*>(xw_gemm),
                            hipFuncAttributeMaxDynamicSharedMemorySize, 139264);
        xw_gemm<<<512, 256, 139264, stream>>>(x, kern, xwT);
        lstm_persist<true><<<NBLK, NTHR, 0, stream>>>(
            x, kern, rker, bias, xwT, seq16, hbuf, flags, out);
    } else {
        lstm_persist<false><<<NBLK, NTHR, 0, stream>>>(
            x, kern, rker, bias, (const f16*)nullptr, seq16, hbuf, flags, out);
    }
    dense_mfma<<<512, 256, 0, stream>>>(seq16, dw, db, out);
}